// Round 1
// baseline (386.378 us; speedup 1.0000x reference)
//
#include <hip/hip_runtime.h>
#include <hip/hip_bf16.h>

// OuterProductMean: b=1, m=256 (MSA), n=384 (seq), C=256, H=32, P=128.
// Pipeline:
//   prep:    woT[p][k] bf16 (128x1024), wT[c][k] bf16 (64x256, wl||wr), bias2[64]
//   cnt:     inv_cnt[i][j] = 1/(sum_m mask[m,i]*mask[m,j] + 1e-3)
//   ln_proj: per-n LN + projection GEMM -> leftT[n*32+c][m], rightT[n*32+d][m] bf16
//   outer:   O = leftT @ rightT^T (12288x12288, K=256) in 128x128 tiles,
//            fused epilogue: O_tile -> LDS bf16 [16 ij][1024 cd] -> @ woT -> out/(cnt)
// Workspace: ~13.5 MB.

typedef float f32x4 __attribute__((ext_vector_type(4)));
typedef __bf16 bf16x8 __attribute__((ext_vector_type(8)));

#define NSEQ 384
#define NMSA 256

// ---------------------------------------------------------------- prep ----
__global__ __launch_bounds__(256) void prep_kernel(
    const float* __restrict__ wl, const float* __restrict__ wr,
    const float* __restrict__ bl, const float* __restrict__ br,
    const float* __restrict__ wo,
    __bf16* __restrict__ woT, __bf16* __restrict__ wT, float* __restrict__ bias2)
{
    int gid = blockIdx.x * 256 + threadIdx.x;
    if (gid < 131072) {                       // woT[p][k] = wo[k][p]
        int p = gid >> 10, k = gid & 1023;
        woT[gid] = (__bf16)wo[k * 128 + p];
    } else if (gid < 131072 + 16384) {        // wT[c][k]: c<32 -> wl, else wr
        int r = gid - 131072;
        int c = r >> 8, k = r & 255;
        wT[r] = (__bf16)(c < 32 ? wl[k * 32 + c] : wr[k * 32 + (c - 32)]);
    } else if (gid < 131072 + 16384 + 64) {
        int c = gid - 147456;
        bias2[c] = (c < 32) ? bl[c] : br[c - 32];
    }
}

// ----------------------------------------------------------------- cnt ----
__global__ __launch_bounds__(256) void cnt_kernel(
    const int* __restrict__ mask, float* __restrict__ inv_cnt)
{
    const int i = blockIdx.x;
    const int t = threadIdx.x;
    __shared__ int mi[NMSA];
    mi[t] = mask[t * NSEQ + i];
    __syncthreads();
    for (int j = t; j < NSEQ; j += 256) {
        int acc = 0;
        for (int m = 0; m < NMSA; ++m)
            acc += mi[m] & mask[m * NSEQ + j];   // mask is 0/1
        inv_cnt[i * NSEQ + j] = 1.0f / ((float)acc + 0.001f);
    }
}

// ------------------------------------------------------------- ln_proj ----
// One block per n. Pass 1: per-thread LN stats for m=tid (streams x row).
// Pass 2: stage xn tile [256 m][32 k] bf16 (row pitch 40 elems = 80B, keeps
// ds_read_b128 2-way-conflict-free), MFMA wT[64 c][k] x xn^T[k][m] -> D[c][m],
// epilogue applies bias+mask and stores transposed (m contiguous per 16 lanes).
__global__ __launch_bounds__(256) void ln_proj_kernel(
    const float* __restrict__ x, const int* __restrict__ mask,
    const float* __restrict__ ln_g, const float* __restrict__ ln_b,
    const __bf16* __restrict__ wT, const float* __restrict__ bias2,
    __bf16* __restrict__ leftT, __bf16* __restrict__ rightT)
{
    const int n = blockIdx.x;
    const int tid = threadIdx.x;
    __shared__ float muS[NMSA], rsS[NMSA], maskS[NMSA];
    __shared__ __bf16 xnT[NMSA * 40];

    {   // pass 1: LN stats, m = tid
        const float* xr = x + ((size_t)tid * NSEQ + n) * 256;
        float s = 0.f, sq = 0.f;
        for (int k = 0; k < 256; k += 4) {
            f32x4 v = *reinterpret_cast<const f32x4*>(xr + k);
            s  += v[0] + v[1] + v[2] + v[3];
            sq += v[0]*v[0] + v[1]*v[1] + v[2]*v[2] + v[3]*v[3];
        }
        float mu = s * (1.f / 256.f);
        float var = sq * (1.f / 256.f) - mu * mu;
        muS[tid] = mu;
        rsS[tid] = rsqrtf(var + 1e-5f);
        maskS[tid] = (float)mask[tid * NSEQ + n];
    }
    __syncthreads();

    const int wid = tid >> 6, lane = tid & 63;
    const int lhi = lane >> 4, llo = lane & 15;
    f32x4 acc[4][4] = {};

    for (int k0 = 0; k0 < 256; k0 += 32) {
        #pragma unroll
        for (int cc = 0; cc < 8; ++cc) {       // stage [256 m][32 k]
            int ch = tid + cc * 256;
            int mR = ch >> 3, c4 = ch & 7;
            f32x4 v  = *reinterpret_cast<const f32x4*>(x + ((size_t)mR * NSEQ + n) * 256 + k0 + c4 * 4);
            f32x4 g  = *reinterpret_cast<const f32x4*>(ln_g + k0 + c4 * 4);
            f32x4 bb = *reinterpret_cast<const f32x4*>(ln_b + k0 + c4 * 4);
            float mu = muS[mR], rs = rsS[mR];
            __bf16* dst = xnT + mR * 40 + c4 * 4;
            dst[0] = (__bf16)((v[0] - mu) * rs * g[0] + bb[0]);
            dst[1] = (__bf16)((v[1] - mu) * rs * g[1] + bb[1]);
            dst[2] = (__bf16)((v[2] - mu) * rs * g[2] + bb[2]);
            dst[3] = (__bf16)((v[3] - mu) * rs * g[3] + bb[3]);
        }
        __syncthreads();
        bf16x8 af[4], bfr[4];
        #pragma unroll
        for (int fr = 0; fr < 4; ++fr)         // A: wT rows c = fr*16+llo
            af[fr] = *reinterpret_cast<const bf16x8*>(wT + (size_t)(fr * 16 + llo) * 256 + k0 + lhi * 8);
        #pragma unroll
        for (int fc = 0; fc < 4; ++fc)         // B: xn cols m = wid*64+fc*16+llo
            bfr[fc] = *reinterpret_cast<const bf16x8*>(xnT + (wid * 64 + fc * 16 + llo) * 40 + lhi * 8);
        #pragma unroll
        for (int fr = 0; fr < 4; ++fr)
            #pragma unroll
            for (int fc = 0; fc < 4; ++fc)
                acc[fr][fc] = __builtin_amdgcn_mfma_f32_16x16x32_bf16(af[fr], bfr[fc], acc[fr][fc], 0, 0, 0);
        __syncthreads();
    }

    // epilogue: D[row=c][col=m]; row=(lane>>4)*4+reg, col=lane&15
    #pragma unroll
    for (int fr = 0; fr < 4; ++fr) {
        #pragma unroll
        for (int fc = 0; fc < 4; ++fc) {
            int mR = wid * 64 + fc * 16 + llo;
            float mv = maskS[mR];
            #pragma unroll
            for (int r = 0; r < 4; ++r) {
                int c = fr * 16 + lhi * 4 + r;
                __bf16 bv = (__bf16)((acc[fr][fc][r] + bias2[c]) * mv);
                if (c < 32) leftT [(size_t)(n * 32 + c)       * 256 + mR] = bv;
                else        rightT[(size_t)(n * 32 + (c - 32)) * 256 + mR] = bv;
            }
        }
    }
}

// --------------------------------------------------------------- outer ----
// Block (bi,bj): 128x128 tile of O = leftT @ rightT^T over K=256 (m), then
// fused projection epilogue. LDS slot-swizzle: 16B slot s at row r stored at
// s^(r&7) -> staged writes and fragment reads both <=2-way conflicts.
__global__ __launch_bounds__(256) void outer_gemm_kernel(
    const __bf16* __restrict__ leftT, const __bf16* __restrict__ rightT,
    const __bf16* __restrict__ woT, const float* __restrict__ bo,
    const float* __restrict__ inv_cnt, float* __restrict__ out)
{
    __shared__ char smem[32768];
    __bf16* Al  = (__bf16*)smem;              // [128][64] swizzled
    __bf16* Bl  = (__bf16*)(smem + 16384);    // [128][64] swizzled
    __bf16* Aep = (__bf16*)smem;              // [16][1024] swizzled (reuse)

    const int tid = threadIdx.x;
    const int bi = blockIdx.x, bj = blockIdx.y;
    const int wid = tid >> 6, lane = tid & 63;
    const int wr = wid >> 1, wc = wid & 1;    // 2x2 waves of 64x64
    const int lhi = lane >> 4, llo = lane & 15;

    f32x4 acc[4][4] = {};

    for (int k0 = 0; k0 < 256; k0 += 64) {
        #pragma unroll
        for (int it = 0; it < 4; ++it) {      // stage 128 rows x 64 k, both tiles
            int ch = tid + it * 256;          // 0..1023
            int r = ch >> 3, s = ch & 7;
            int ss = s ^ (r & 7);
            *reinterpret_cast<bf16x8*>(Al + r * 64 + ss * 8) =
                *reinterpret_cast<const bf16x8*>(leftT  + (size_t)(bi * 128 + r) * 256 + k0 + s * 8);
            *reinterpret_cast<bf16x8*>(Bl + r * 64 + ss * 8) =
                *reinterpret_cast<const bf16x8*>(rightT + (size_t)(bj * 128 + r) * 256 + k0 + s * 8);
        }
        __syncthreads();
        #pragma unroll
        for (int kk = 0; kk < 64; kk += 32) {
            bf16x8 af[4], bfr[4];
            int slot0 = (kk >> 3) + lhi;
            #pragma unroll
            for (int fr = 0; fr < 4; ++fr) {
                int row = wr * 64 + fr * 16 + llo;
                af[fr] = *reinterpret_cast<const bf16x8*>(Al + row * 64 + (slot0 ^ (row & 7)) * 8);
            }
            #pragma unroll
            for (int fc = 0; fc < 4; ++fc) {
                int row = wc * 64 + fc * 16 + llo;
                bfr[fc] = *reinterpret_cast<const bf16x8*>(Bl + row * 64 + (slot0 ^ (row & 7)) * 8);
            }
            #pragma unroll
            for (int fr = 0; fr < 4; ++fr)
                #pragma unroll
                for (int fc = 0; fc < 4; ++fc)
                    acc[fr][fc] = __builtin_amdgcn_mfma_f32_16x16x32_bf16(af[fr], bfr[fc], acc[fr][fc], 0, 0, 0);
        }
        __syncthreads();
    }

    // O tile -> LDS bf16 A_ep[16 ij][1024 cd]; ij=il*4+jl, cd=c*32+d
    #pragma unroll
    for (int fr = 0; fr < 4; ++fr) {
        #pragma unroll
        for (int fc = 0; fc < 4; ++fc) {
            int gj = wc * 64 + fc * 16 + llo;
            int jl = gj >> 5, d = gj & 31;
            #pragma unroll
            for (int r = 0; r < 4; ++r) {
                int gi = wr * 64 + fr * 16 + lhi * 4 + r;
                int il = gi >> 5, c = gi & 31;
                int ij = il * 4 + jl;
                int cd = c * 32 + d;
                int s = cd >> 3;
                Aep[ij * 1024 + ((s ^ (ij & 7)) << 3) + (cd & 7)] = (__bf16)acc[fr][fc][r];
            }
        }
    }
    __syncthreads();

    // epilogue GEMM: [16 ij][1024] @ woT^T slice -> wave handles p in [wid*32, wid*32+32)
    f32x4 eacc[2] = {};
    const int pbase = wid * 32;
    for (int k0 = 0; k0 < 1024; k0 += 32) {
        int s0 = (k0 >> 3) + lhi;
        bf16x8 a = *reinterpret_cast<const bf16x8*>(Aep + llo * 1024 + ((s0 ^ (llo & 7)) << 3));
        #pragma unroll
        for (int fc = 0; fc < 2; ++fc) {
            int p = pbase + fc * 16 + llo;
            bf16x8 b = *reinterpret_cast<const bf16x8*>(woT + (size_t)p * 1024 + k0 + lhi * 8);
            eacc[fc] = __builtin_amdgcn_mfma_f32_16x16x32_bf16(a, b, eacc[fc], 0, 0, 0);
        }
    }
    #pragma unroll
    for (int fc = 0; fc < 2; ++fc) {
        int p = pbase + fc * 16 + llo;
        float bov = bo[p];
        #pragma unroll
        for (int r = 0; r < 4; ++r) {
            int ij = lhi * 4 + r;
            int i = bi * 4 + (ij >> 2);
            int j = bj * 4 + (ij & 3);
            out[(size_t)(i * NSEQ + j) * 128 + p] = (eacc[fc][r] + bov) * inv_cnt[i * NSEQ + j];
        }
    }
}

// -------------------------------------------------------------- launch ----
extern "C" void kernel_launch(void* const* d_in, const int* in_sizes, int n_in,
                              void* d_out, int out_size, void* d_ws, size_t ws_size,
                              hipStream_t stream) {
    const float* x    = (const float*)d_in[0];
    const int*   mask = (const int*)  d_in[1];
    const float* ln_g = (const float*)d_in[2];
    const float* ln_b = (const float*)d_in[3];
    const float* wl   = (const float*)d_in[4];
    const float* bl   = (const float*)d_in[5];
    const float* wr   = (const float*)d_in[6];
    const float* br   = (const float*)d_in[7];
    const float* wo   = (const float*)d_in[8];
    const float* bo   = (const float*)d_in[9];
    float* out = (float*)d_out;

    char* ws = (char*)d_ws;
    __bf16* leftT   = (__bf16*)(ws);             // 12288*256*2 = 6,291,456
    __bf16* rightT  = (__bf16*)(ws + 6291456);   // 6,291,456
    __bf16* woT     = (__bf16*)(ws + 12582912);  // 262,144
    __bf16* wT      = (__bf16*)(ws + 12845056);  // 32,768
    float*  bias2   = (float*) (ws + 12877824);  // 256
    float*  inv_cnt = (float*) (ws + 12878080);  // 589,824  (end ~13.5 MB)

    prep_kernel<<<577, 256, 0, stream>>>(wl, wr, bl, br, wo, woT, wT, bias2);
    cnt_kernel<<<NSEQ, 256, 0, stream>>>(mask, inv_cnt);
    ln_proj_kernel<<<NSEQ, 256, 0, stream>>>(x, mask, ln_g, ln_b, wT, bias2, leftT, rightT);
    dim3 grid(96, 96);
    outer_gemm_kernel<<<grid, 256, 0, stream>>>(leftT, rightT, woT, bo, inv_cnt, out);
}

// Round 2
// 220.088 us; speedup vs baseline: 1.7556x; 1.7556x over previous
//
#include <hip/hip_runtime.h>
#include <hip/hip_bf16.h>
#include <stdint.h>

// OuterProductMean: b=1, m=256 (MSA), n=384 (seq), C=256, H=32, P=128.
//   prep:    woT[p][k] bf16 (128x1024), wT[c][k] bf16 (64x256, wl||wr), bias2[64]
//   cnt:     inv_cnt[i][j] = 1/(sum_m mask[m,i]*mask[m,j] + 1e-3)
//   ln_proj: per-n LN + projection GEMM -> leftT[n*32+c][m], rightT[n*32+d][m] bf16
//   outer:   O = leftT @ rightT^T in 256x256 tiles (K=256, global_load_lds dbuf,
//            counted vmcnt), fused epilogue: O-tile -> LDS bf16 [64 ij][1024 cd]
//            -> @ woT -> out * inv_cnt. Grid 48x48, XCD-chunked remap.

typedef float f32x4 __attribute__((ext_vector_type(4)));
typedef __bf16 bf16x8 __attribute__((ext_vector_type(8)));

#define NSEQ 384
#define NMSA 256

typedef const __attribute__((address_space(1))) unsigned int* gptr_t;
typedef __attribute__((address_space(3))) unsigned int* lptr_t;

__device__ __forceinline__ void gload_lds16(const void* g, void* l) {
    __builtin_amdgcn_global_load_lds((gptr_t)g, (lptr_t)l, 16, 0, 0);
}

// ---------------------------------------------------------------- prep ----
__global__ __launch_bounds__(256) void prep_kernel(
    const float* __restrict__ wl, const float* __restrict__ wr,
    const float* __restrict__ bl, const float* __restrict__ br,
    const float* __restrict__ wo,
    __bf16* __restrict__ woT, __bf16* __restrict__ wT, float* __restrict__ bias2)
{
    int gid = blockIdx.x * 256 + threadIdx.x;
    if (gid < 131072) {                       // woT[p][k] = wo[k][p]
        int p = gid >> 10, k = gid & 1023;
        woT[gid] = (__bf16)wo[k * 128 + p];
    } else if (gid < 131072 + 16384) {        // wT[c][k]: c<32 -> wl, else wr
        int r = gid - 131072;
        int c = r >> 8, k = r & 255;
        wT[r] = (__bf16)(c < 32 ? wl[k * 32 + c] : wr[k * 32 + (c - 32)]);
    } else if (gid < 131072 + 16384 + 64) {
        int c = gid - 147456;
        bias2[c] = (c < 32) ? bl[c] : br[c - 32];
    }
}

// ----------------------------------------------------------------- cnt ----
__global__ __launch_bounds__(256) void cnt_kernel(
    const int* __restrict__ mask, float* __restrict__ inv_cnt)
{
    const int i = blockIdx.x;
    const int t = threadIdx.x;
    __shared__ int mi[NMSA];
    mi[t] = mask[t * NSEQ + i];
    __syncthreads();
    for (int j = t; j < NSEQ; j += 256) {
        int acc = 0;
        for (int m = 0; m < NMSA; ++m)
            acc += mi[m] & mask[m * NSEQ + j];
        inv_cnt[i * NSEQ + j] = 1.0f / ((float)acc + 0.001f);
    }
}

// ------------------------------------------------------------- ln_proj ----
__global__ __launch_bounds__(256) void ln_proj_kernel(
    const float* __restrict__ x, const int* __restrict__ mask,
    const float* __restrict__ ln_g, const float* __restrict__ ln_b,
    const __bf16* __restrict__ wT, const float* __restrict__ bias2,
    __bf16* __restrict__ leftT, __bf16* __restrict__ rightT)
{
    const int n = blockIdx.x;
    const int tid = threadIdx.x;
    __shared__ float muS[NMSA], rsS[NMSA], maskS[NMSA];
    __shared__ __bf16 xnT[NMSA * 40];

    {   // pass 1: LN stats, m = tid
        const float* xr = x + ((size_t)tid * NSEQ + n) * 256;
        float s = 0.f, sq = 0.f;
        for (int k = 0; k < 256; k += 4) {
            f32x4 v = *reinterpret_cast<const f32x4*>(xr + k);
            s  += v[0] + v[1] + v[2] + v[3];
            sq += v[0]*v[0] + v[1]*v[1] + v[2]*v[2] + v[3]*v[3];
        }
        float mu = s * (1.f / 256.f);
        float var = sq * (1.f / 256.f) - mu * mu;
        muS[tid] = mu;
        rsS[tid] = rsqrtf(var + 1e-5f);
        maskS[tid] = (float)mask[tid * NSEQ + n];
    }
    __syncthreads();

    const int wid = tid >> 6, lane = tid & 63;
    const int lhi = lane >> 4, llo = lane & 15;
    f32x4 acc[4][4] = {};

    for (int k0 = 0; k0 < 256; k0 += 32) {
        #pragma unroll
        for (int cc = 0; cc < 8; ++cc) {       // stage [256 m][32 k]
            int ch = tid + cc * 256;
            int mR = ch >> 3, c4 = ch & 7;
            f32x4 v  = *reinterpret_cast<const f32x4*>(x + ((size_t)mR * NSEQ + n) * 256 + k0 + c4 * 4);
            f32x4 g  = *reinterpret_cast<const f32x4*>(ln_g + k0 + c4 * 4);
            f32x4 bb = *reinterpret_cast<const f32x4*>(ln_b + k0 + c4 * 4);
            float mu = muS[mR], rs = rsS[mR];
            __bf16* dst = xnT + mR * 40 + c4 * 4;
            dst[0] = (__bf16)((v[0] - mu) * rs * g[0] + bb[0]);
            dst[1] = (__bf16)((v[1] - mu) * rs * g[1] + bb[1]);
            dst[2] = (__bf16)((v[2] - mu) * rs * g[2] + bb[2]);
            dst[3] = (__bf16)((v[3] - mu) * rs * g[3] + bb[3]);
        }
        __syncthreads();
        bf16x8 af[4], bfr[4];
        #pragma unroll
        for (int fr = 0; fr < 4; ++fr)
            af[fr] = *reinterpret_cast<const bf16x8*>(wT + (size_t)(fr * 16 + llo) * 256 + k0 + lhi * 8);
        #pragma unroll
        for (int fc = 0; fc < 4; ++fc)
            bfr[fc] = *reinterpret_cast<const bf16x8*>(xnT + (wid * 64 + fc * 16 + llo) * 40 + lhi * 8);
        #pragma unroll
        for (int fr = 0; fr < 4; ++fr)
            #pragma unroll
            for (int fc = 0; fc < 4; ++fc)
                acc[fr][fc] = __builtin_amdgcn_mfma_f32_16x16x32_bf16(af[fr], bfr[fc], acc[fr][fc], 0, 0, 0);
        __syncthreads();
    }

    #pragma unroll
    for (int fr = 0; fr < 4; ++fr) {
        #pragma unroll
        for (int fc = 0; fc < 4; ++fc) {
            int mR = wid * 64 + fc * 16 + llo;
            float mv = maskS[mR];
            #pragma unroll
            for (int r = 0; r < 4; ++r) {
                int c = fr * 16 + lhi * 4 + r;
                __bf16 bv = (__bf16)((acc[fr][fc][r] + bias2[c]) * mv);
                if (c < 32) leftT [(size_t)(n * 32 + c)        * 256 + mR] = bv;
                else        rightT[(size_t)(n * 32 + (c - 32)) * 256 + mR] = bv;
            }
        }
    }
}

// --------------------------------------------------------------- outer ----
// 256x256 tile, K=256 in 4 steps of BK=64, 8 waves (2x4) of 128x64.
// LDS: 2 x (A 32KB + B 32KB) = 128KB, overlaid by A_ep[64][1024] bf16 for the
// fused projection epilogue. Staging via global_load_lds dwordx4: linear LDS
// dest, inverse-XOR-swizzled global source; reads use slot ^= (row&7).
__global__ __launch_bounds__(512, 2) void outer_gemm_kernel(
    const __bf16* __restrict__ leftT, const __bf16* __restrict__ rightT,
    const __bf16* __restrict__ woT, const float* __restrict__ bo,
    const float* __restrict__ inv_cnt, float* __restrict__ out)
{
    __shared__ char smem[131072];
    const int tid = threadIdx.x;
    const int wid = tid >> 6, lane = tid & 63;
    const int lhi = lane >> 4, llo = lane & 15;
    const int wr = wid >> 2, wc = wid & 3;     // 2x4 wave grid, wave = 128x64

    // XCD-chunked remap (2304 = 8 * 288, bijective): consecutive logical ids
    // land on one XCD; column-major within XCD so the B/wo panels stay L2-hot.
    int wg = blockIdx.x;
    int l  = (wg & 7) * 288 + (wg >> 3);
    int bj = l / 48, bi = l % 48;

    char* Abuf[2] = { smem,         smem + 65536 };
    char* Bbuf[2] = { smem + 32768, smem + 98304 };

    // stage one BK=64 tile pair: chunk q = it*512 + wid*64 + lane (0..2047),
    // LDS row r = q>>3 slot ss = q&7; source slot s = ss ^ (r&7).
    auto STAGE = [&](int buf, int k0) {
        #pragma unroll
        for (int it = 0; it < 4; ++it) {
            int q = it * 512 + wid * 64 + lane;
            int r = q >> 3;
            int s = (q & 7) ^ (r & 7);
            int ldsoff = (it * 512 + wid * 64) * 16;        // wave-uniform
            gload_lds16(leftT  + (size_t)(bi * 256 + r) * 256 + k0 + s * 8, Abuf[buf] + ldsoff);
            gload_lds16(rightT + (size_t)(bj * 256 + r) * 256 + k0 + s * 8, Bbuf[buf] + ldsoff);
        }
    };

    f32x4 acc[8][4] = {};

    STAGE(0, 0);
    #pragma unroll
    for (int t = 0; t < 4; ++t) {
        if (t < 3) {
            STAGE((t + 1) & 1, (t + 1) * 64);
            asm volatile("s_waitcnt vmcnt(8)" ::: "memory");
        } else {
            asm volatile("s_waitcnt vmcnt(0)" ::: "memory");
        }
        __builtin_amdgcn_s_barrier();
        __builtin_amdgcn_sched_barrier(0);
        const __bf16* Al = (const __bf16*)Abuf[t & 1];
        const __bf16* Bl = (const __bf16*)Bbuf[t & 1];
        #pragma unroll
        for (int kk = 0; kk < 2; ++kk) {
            bf16x8 af[8], bfv[4];
            int sb = kk * 4 + lhi;
            #pragma unroll
            for (int fr = 0; fr < 8; ++fr) {
                int row = wr * 128 + fr * 16 + llo;
                af[fr] = *(const bf16x8*)(Al + row * 64 + ((sb ^ (row & 7)) << 3));
            }
            #pragma unroll
            for (int fc = 0; fc < 4; ++fc) {
                int row = wc * 64 + fc * 16 + llo;
                bfv[fc] = *(const bf16x8*)(Bl + row * 64 + ((sb ^ (row & 7)) << 3));
            }
            #pragma unroll
            for (int fr = 0; fr < 8; ++fr)
                #pragma unroll
                for (int fc = 0; fc < 4; ++fc)
                    acc[fr][fc] = __builtin_amdgcn_mfma_f32_16x16x32_bf16(af[fr], bfv[fc], acc[fr][fc], 0, 0, 0);
        }
        __builtin_amdgcn_sched_barrier(0);
        __builtin_amdgcn_s_barrier();
    }

    // O-tile -> A_ep[64 ij][1024 cd] bf16 (overlays main bufs; last barrier done)
    // swizzle: 16B slot s at row ij stored at s ^ ((s>>4)&7) ^ (ij&7)
    __bf16* Aep = (__bf16*)smem;
    #pragma unroll
    for (int fr = 0; fr < 8; ++fr) {
        #pragma unroll
        for (int fc = 0; fc < 4; ++fc) {
            int gj = wc * 64 + fc * 16 + llo;
            int jl = gj >> 5, d = gj & 31;
            #pragma unroll
            for (int r = 0; r < 4; ++r) {
                int gi = wr * 128 + fr * 16 + lhi * 4 + r;
                int il = gi >> 5, c = gi & 31;
                int ij = il * 8 + jl;
                int cd = c * 32 + d;
                int s = cd >> 3;
                int ss = s ^ ((s >> 4) & 7) ^ (ij & 7);
                Aep[ij * 1024 + (ss << 3) + (cd & 7)] = (__bf16)acc[fr][fc][r];
            }
        }
    }
    __builtin_amdgcn_s_barrier();
    __builtin_amdgcn_sched_barrier(0);

    // epilogue GEMM: [64 ij][1024] @ woT[p][1024]^T, wave owns p = wid*16+llo
    f32x4 eacc[4] = {};
    const int p = wid * 16 + llo;
    const __bf16* wrow = woT + (size_t)p * 1024 + lhi * 8;
    #pragma unroll 4
    for (int k0 = 0; k0 < 1024; k0 += 32) {
        int sb = (k0 >> 3) + lhi;
        bf16x8 bw = *(const bf16x8*)(wrow + k0);
        #pragma unroll
        for (int mf = 0; mf < 4; ++mf) {
            int ij = mf * 16 + llo;
            int ss = sb ^ ((sb >> 4) & 7) ^ (ij & 7);
            bf16x8 a = *(const bf16x8*)(Aep + ij * 1024 + (ss << 3));
            eacc[mf] = __builtin_amdgcn_mfma_f32_16x16x32_bf16(a, bw, eacc[mf], 0, 0, 0);
        }
    }

    const float bov = bo[p];
    #pragma unroll
    for (int mf = 0; mf < 4; ++mf) {
        #pragma unroll
        for (int r = 0; r < 4; ++r) {
            int ij = mf * 16 + lhi * 4 + r;
            int i = bi * 8 + (ij >> 3);
            int j = bj * 8 + (ij & 7);
            size_t idx = (size_t)i * NSEQ + j;
            out[idx * 128 + p] = (eacc[mf][r] + bov) * inv_cnt[idx];
        }
    }
}

// -------------------------------------------------------------- launch ----
extern "C" void kernel_launch(void* const* d_in, const int* in_sizes, int n_in,
                              void* d_out, int out_size, void* d_ws, size_t ws_size,
                              hipStream_t stream) {
    const float* x    = (const float*)d_in[0];
    const int*   mask = (const int*)  d_in[1];
    const float* ln_g = (const float*)d_in[2];
    const float* ln_b = (const float*)d_in[3];
    const float* wl   = (const float*)d_in[4];
    const float* bl   = (const float*)d_in[5];
    const float* wr   = (const float*)d_in[6];
    const float* br   = (const float*)d_in[7];
    const float* wo   = (const float*)d_in[8];
    const float* bo   = (const float*)d_in[9];
    float* out = (float*)d_out;

    char* ws = (char*)d_ws;
    __bf16* leftT   = (__bf16*)(ws);             // 6,291,456
    __bf16* rightT  = (__bf16*)(ws + 6291456);   // 6,291,456
    __bf16* woT     = (__bf16*)(ws + 12582912);  // 262,144
    __bf16* wT      = (__bf16*)(ws + 12845056);  // 32,768
    float*  bias2   = (float*) (ws + 12877824);  // 256
    float*  inv_cnt = (float*) (ws + 12878080);  // 589,824

    prep_kernel<<<577, 256, 0, stream>>>(wl, wr, bl, br, wo, woT, wT, bias2);
    cnt_kernel<<<NSEQ, 256, 0, stream>>>(mask, inv_cnt);
    ln_proj_kernel<<<NSEQ, 256, 0, stream>>>(x, mask, ln_g, ln_b, wT, bias2, leftT, rightT);
    outer_gemm_kernel<<<2304, 512, 0, stream>>>(leftT, rightT, woT, bo, inv_cnt, out);
}

// Round 3
// 218.583 us; speedup vs baseline: 1.7677x; 1.0069x over previous
//
#include <hip/hip_runtime.h>
#include <hip/hip_bf16.h>
#include <stdint.h>

// OuterProductMean: b=1, m=256 (MSA), n=384 (seq), C=256, H=32, P=128.
//   prep:    woT[p][cd'] bf16 with cd' = d*32+c  (k = c*32+d reordered)
//   prep_wg: wg[c][k] = w[k][c]*ln_g[k] bf16; Gc[c]=sum_k wg; B2[c]=sum_k w*ln_b + bias
//   cnt:     inv_cnt[i][j] = 1/(sum_m mask[m,i]*mask[m,j] + 1e-3)
//   ln_proj: single-pass: stage raw x bf16 + stats on the fly; MFMA wg @ x;
//            epilogue rs*(acc - mu*G) + B2, mask -> leftT/rightT [n*32+c][m]
//   outer:   O = leftT @ rightT^T 256x256 tiles (K=256, global_load_lds dbuf,
//            counted vmcnt); epilogue: A_ep[2 half][64 ij][512 cd] bf16
//            (slot-swizzled), K-split GEMM vs woT, LDS f32 reduction, store.

typedef float f32x4 __attribute__((ext_vector_type(4)));
typedef __bf16 bf16x8 __attribute__((ext_vector_type(8)));
typedef __bf16 bf16x4 __attribute__((ext_vector_type(4)));

#define NSEQ 384
#define NMSA 256

typedef const __attribute__((address_space(1))) unsigned int* gptr_t;
typedef __attribute__((address_space(3))) unsigned int* lptr_t;

__device__ __forceinline__ void gload_lds16(const void* g, void* l) {
    __builtin_amdgcn_global_load_lds((gptr_t)g, (lptr_t)l, 16, 0, 0);
}

// ---------------------------------------------------------------- prep ----
// woT[p*1024 + d*32 + c] = wo[(c*32+d)*128 + p]
__global__ __launch_bounds__(256) void prep_kernel(
    const float* __restrict__ wo, __bf16* __restrict__ woT)
{
    int gid = blockIdx.x * 256 + threadIdx.x;   // 131072 total
    int p = gid >> 10, q = gid & 1023;
    int d = q >> 5, c = q & 31;
    woT[gid] = (__bf16)wo[(c * 32 + d) * 128 + p];
}

// wg[c][k] bf16, Gc[c] = sum_k (bf16)(w*g), B2[c] = sum_k w*b + bias_c
__global__ __launch_bounds__(256) void prep_wg_kernel(
    const float* __restrict__ wl, const float* __restrict__ wr,
    const float* __restrict__ bl, const float* __restrict__ br,
    const float* __restrict__ ln_g, const float* __restrict__ ln_b,
    __bf16* __restrict__ wg, float* __restrict__ Gc, float* __restrict__ B2)
{
    const int c = blockIdx.x;      // 0..63
    const int k = threadIdx.x;     // 0..255
    float w = (c < 32) ? wl[k * 32 + c] : wr[k * 32 + (c - 32)];
    __bf16 wgb = (__bf16)(w * ln_g[k]);
    wg[c * 256 + k] = wgb;
    float gsum = (float)wgb;       // rounded value so mu-term cancels exactly
    float bsum = w * ln_b[k];
    __shared__ float sg[4], sb[4];
    for (int off = 32; off; off >>= 1) {
        gsum += __shfl_down(gsum, off);
        bsum += __shfl_down(bsum, off);
    }
    int wid = k >> 6, lane = k & 63;
    if (lane == 0) { sg[wid] = gsum; sb[wid] = bsum; }
    __syncthreads();
    if (k == 0) {
        Gc[c] = sg[0] + sg[1] + sg[2] + sg[3];
        B2[c] = sb[0] + sb[1] + sb[2] + sb[3] + ((c < 32) ? bl[c] : br[c - 32]);
    }
}

// ----------------------------------------------------------------- cnt ----
__global__ __launch_bounds__(256) void cnt_kernel(
    const int* __restrict__ mask, float* __restrict__ inv_cnt)
{
    const int i = blockIdx.x;
    const int t = threadIdx.x;
    __shared__ int mi[NMSA];
    mi[t] = mask[t * NSEQ + i];
    __syncthreads();
    for (int j = t; j < NSEQ; j += 256) {
        int acc = 0;
        for (int m = 0; m < NMSA; ++m)
            acc += mi[m] & mask[m * NSEQ + j];
        inv_cnt[i * NSEQ + j] = 1.0f / ((float)acc + 0.001f);
    }
}

// ------------------------------------------------------------- ln_proj ----
__global__ __launch_bounds__(256) void ln_proj_kernel(
    const float* __restrict__ x, const int* __restrict__ mask,
    const __bf16* __restrict__ wg, const float* __restrict__ Gc,
    const float* __restrict__ B2,
    __bf16* __restrict__ leftT, __bf16* __restrict__ rightT)
{
    const int n = blockIdx.x;
    const int tid = threadIdx.x;
    __shared__ __bf16 xnT[NMSA * 40];
    __shared__ float muS[NMSA], rsS[NMSA], maskS[NMSA], GcS[64], B2S[64];

    if (tid < 64) { GcS[tid] = Gc[tid]; B2S[tid] = B2[tid]; }
    maskS[tid] = (float)mask[tid * NSEQ + n];

    const int wid = tid >> 6, lane = tid & 63;
    const int lhi = lane >> 4, llo = lane & 15;
    float ps[8] = {}, pq[8] = {};
    f32x4 acc[4][4] = {};

    for (int k0 = 0; k0 < 256; k0 += 32) {
        #pragma unroll
        for (int cc = 0; cc < 8; ++cc) {       // stage raw x [256 m][32 k] bf16
            int ch = tid + cc * 256;
            int mR = ch >> 3, c4 = ch & 7;
            f32x4 v = *reinterpret_cast<const f32x4*>(x + ((size_t)mR * NSEQ + n) * 256 + k0 + c4 * 4);
            ps[cc] += v[0] + v[1] + v[2] + v[3];
            pq[cc] += v[0]*v[0] + v[1]*v[1] + v[2]*v[2] + v[3]*v[3];
            __bf16* dst = xnT + mR * 40 + c4 * 4;
            dst[0] = (__bf16)v[0]; dst[1] = (__bf16)v[1];
            dst[2] = (__bf16)v[2]; dst[3] = (__bf16)v[3];
        }
        __syncthreads();
        bf16x8 af[4], bfr[4];
        #pragma unroll
        for (int fr = 0; fr < 4; ++fr)
            af[fr] = *reinterpret_cast<const bf16x8*>(wg + (size_t)(fr * 16 + llo) * 256 + k0 + lhi * 8);
        #pragma unroll
        for (int fc = 0; fc < 4; ++fc)
            bfr[fc] = *reinterpret_cast<const bf16x8*>(xnT + (wid * 64 + fc * 16 + llo) * 40 + lhi * 8);
        #pragma unroll
        for (int fr = 0; fr < 4; ++fr)
            #pragma unroll
            for (int fc = 0; fc < 4; ++fc)
                acc[fr][fc] = __builtin_amdgcn_mfma_f32_16x16x32_bf16(af[fr], bfr[fc], acc[fr][fc], 0, 0, 0);
        __syncthreads();
    }

    // stats: rows mR = tid>>3 + cc*32, 8 lanes (c4) per row -> shfl reduce
    #pragma unroll
    for (int cc = 0; cc < 8; ++cc) {
        float s = ps[cc], q = pq[cc];
        s += __shfl_xor(s, 1); q += __shfl_xor(q, 1);
        s += __shfl_xor(s, 2); q += __shfl_xor(q, 2);
        s += __shfl_xor(s, 4); q += __shfl_xor(q, 4);
        if ((tid & 7) == 0) {
            int m = (tid >> 3) + cc * 32;
            float mu = s * (1.f / 256.f);
            float var = q * (1.f / 256.f) - mu * mu;
            muS[m] = mu;
            rsS[m] = rsqrtf(var + 1e-5f);
        }
    }
    __syncthreads();

    // epilogue: D[row=c][col=m]; out = rs*(acc - mu*G_c) + B2_c, then mask
    #pragma unroll
    for (int fr = 0; fr < 4; ++fr) {
        #pragma unroll
        for (int fc = 0; fc < 4; ++fc) {
            int mR = wid * 64 + fc * 16 + llo;
            float mv = maskS[mR], rs = rsS[mR], mu = muS[mR];
            #pragma unroll
            for (int r = 0; r < 4; ++r) {
                int c = fr * 16 + lhi * 4 + r;
                float val = (acc[fr][fc][r] - mu * GcS[c]) * rs + B2S[c];
                __bf16 bv = (__bf16)(val * mv);
                if (c < 32) leftT [(size_t)(n * 32 + c)        * 256 + mR] = bv;
                else        rightT[(size_t)(n * 32 + (c - 32)) * 256 + mR] = bv;
            }
        }
    }
}

// --------------------------------------------------------------- outer ----
__global__ __launch_bounds__(512, 2) void outer_gemm_kernel(
    const __bf16* __restrict__ leftT, const __bf16* __restrict__ rightT,
    const __bf16* __restrict__ woT, const float* __restrict__ bo,
    const float* __restrict__ inv_cnt, float* __restrict__ out)
{
    __shared__ char smem[131072];
    const int tid = threadIdx.x;
    const int wid = tid >> 6, lane = tid & 63;
    const int lhi = lane >> 4, llo = lane & 15;
    const int wr = wid >> 2, wc = wid & 3;     // 2x4 wave grid, wave = 128x64

    int wg_ = blockIdx.x;
    int l  = (wg_ & 7) * 288 + (wg_ >> 3);     // XCD-chunked remap (2304 = 8*288)
    int bj = l / 48, bi = l % 48;

    char* Abuf[2] = { smem,         smem + 65536 };
    char* Bbuf[2] = { smem + 32768, smem + 98304 };

    auto STAGE = [&](int buf, int k0) {
        #pragma unroll
        for (int it = 0; it < 4; ++it) {
            int q = it * 512 + wid * 64 + lane;
            int r = q >> 3;
            int s = (q & 7) ^ (r & 7);
            int ldsoff = (it * 512 + wid * 64) * 16;        // wave-uniform
            gload_lds16(leftT  + (size_t)(bi * 256 + r) * 256 + k0 + s * 8, Abuf[buf] + ldsoff);
            gload_lds16(rightT + (size_t)(bj * 256 + r) * 256 + k0 + s * 8, Bbuf[buf] + ldsoff);
        }
    };

    f32x4 acc[8][4] = {};

    STAGE(0, 0);
    #pragma unroll
    for (int t = 0; t < 4; ++t) {
        if (t < 3) {
            STAGE((t + 1) & 1, (t + 1) * 64);
            asm volatile("s_waitcnt vmcnt(8)" ::: "memory");
        } else {
            asm volatile("s_waitcnt vmcnt(0)" ::: "memory");
        }
        __builtin_amdgcn_s_barrier();
        __builtin_amdgcn_sched_barrier(0);
        const __bf16* Al = (const __bf16*)Abuf[t & 1];
        const __bf16* Bl = (const __bf16*)Bbuf[t & 1];
        #pragma unroll
        for (int kk = 0; kk < 2; ++kk) {
            bf16x8 af[8], bfv[4];
            int sb = kk * 4 + lhi;
            #pragma unroll
            for (int fr = 0; fr < 8; ++fr) {
                int row = wr * 128 + fr * 16 + llo;
                af[fr] = *(const bf16x8*)(Al + row * 64 + ((sb ^ (row & 7)) << 3));
            }
            #pragma unroll
            for (int fc = 0; fc < 4; ++fc) {
                int row = wc * 64 + fc * 16 + llo;
                bfv[fc] = *(const bf16x8*)(Bl + row * 64 + ((sb ^ (row & 7)) << 3));
            }
            #pragma unroll
            for (int fr = 0; fr < 8; ++fr)
                #pragma unroll
                for (int fc = 0; fc < 4; ++fc)
                    acc[fr][fc] = __builtin_amdgcn_mfma_f32_16x16x32_bf16(af[fr], bfv[fc], acc[fr][fc], 0, 0, 0);
        }
        __builtin_amdgcn_sched_barrier(0);
        __builtin_amdgcn_s_barrier();
    }

    // ---- phase 1: O-tile -> A_ep[2 half][64 ij][512 cd_local] bf16 ----
    // cd' = d*32+c; half = cd'>>9 = fc&1; cd_local = llo*32 + c
    // slot t = llo*4 + (fr&1)*2 + (lhi>>1); swizzle tp = t ^ ((t>>3)&7) ^ (ij&7)
    __bf16* Aep = (__bf16*)smem;
    #pragma unroll
    for (int fr = 0; fr < 8; ++fr) {
        #pragma unroll
        for (int fc = 0; fc < 4; ++fc) {
            int ij = (wr * 4 + (fr >> 1)) * 8 + wc * 2 + (fc >> 1);
            int half = fc & 1;
            int t = llo * 4 + (fr & 1) * 2 + (lhi >> 1);
            int tp = t ^ ((t >> 3) & 7) ^ (ij & 7);
            bf16x4 v;
            v[0] = (__bf16)acc[fr][fc][0]; v[1] = (__bf16)acc[fr][fc][1];
            v[2] = (__bf16)acc[fr][fc][2]; v[3] = (__bf16)acc[fr][fc][3];
            *(bf16x4*)(Aep + half * 32768 + ij * 512 + tp * 8 + (lhi & 1) * 4) = v;
        }
    }
    __syncthreads();

    // ---- phase 2: K-split epilogue GEMM: wave (kw, nw), M=64 N=32 K=512 ----
    const int kw = wid & 1, nw = wid >> 1;
    const __bf16* Asrc = Aep + kw * 32768;
    f32x4 eacc[4][2] = {};
    #pragma unroll 2
    for (int k0 = 0; k0 < 512; k0 += 32) {
        bf16x8 bw0 = *(const bf16x8*)(woT + (size_t)(nw * 32 + llo)      * 1024 + kw * 512 + k0 + lhi * 8);
        bf16x8 bw1 = *(const bf16x8*)(woT + (size_t)(nw * 32 + 16 + llo) * 1024 + kw * 512 + k0 + lhi * 8);
        int t = (k0 >> 3) + lhi;
        int txor = (t >> 3) & 7;
        #pragma unroll
        for (int mf = 0; mf < 4; ++mf) {
            int ij = mf * 16 + llo;
            int tp = t ^ txor ^ (ij & 7);
            bf16x8 a = *(const bf16x8*)(Asrc + ij * 512 + tp * 8);
            eacc[mf][0] = __builtin_amdgcn_mfma_f32_16x16x32_bf16(a, bw0, eacc[mf][0], 0, 0, 0);
            eacc[mf][1] = __builtin_amdgcn_mfma_f32_16x16x32_bf16(a, bw1, eacc[mf][1], 0, 0, 0);
        }
    }
    __syncthreads();

    // ---- phase 3: cross-kw reduction via f32 scratch (pitch 132), store ----
    float* scratch = (float*)smem;             // [64][132] f32 = 33792 B
    if (kw == 1) {
        #pragma unroll
        for (int mf = 0; mf < 4; ++mf)
            #pragma unroll
            for (int pf = 0; pf < 2; ++pf) {
                int p = nw * 32 + pf * 16 + llo;
                #pragma unroll
                for (int r = 0; r < 4; ++r)
                    scratch[(mf * 16 + lhi * 4 + r) * 132 + p] = eacc[mf][pf][r];
            }
    }
    __syncthreads();
    if (kw == 0) {
        #pragma unroll
        for (int mf = 0; mf < 4; ++mf)
            #pragma unroll
            for (int pf = 0; pf < 2; ++pf) {
                int p = nw * 32 + pf * 16 + llo;
                float bov = bo[p];
                #pragma unroll
                for (int r = 0; r < 4; ++r) {
                    int ij = mf * 16 + lhi * 4 + r;
                    int i = bi * 8 + (ij >> 3), j = bj * 8 + (ij & 7);
                    size_t idx = (size_t)i * NSEQ + j;
                    out[idx * 128 + p] = (eacc[mf][pf][r] + scratch[ij * 132 + p] + bov) * inv_cnt[idx];
                }
            }
    }
}

// -------------------------------------------------------------- launch ----
extern "C" void kernel_launch(void* const* d_in, const int* in_sizes, int n_in,
                              void* d_out, int out_size, void* d_ws, size_t ws_size,
                              hipStream_t stream) {
    const float* x    = (const float*)d_in[0];
    const int*   mask = (const int*)  d_in[1];
    const float* ln_g = (const float*)d_in[2];
    const float* ln_b = (const float*)d_in[3];
    const float* wl   = (const float*)d_in[4];
    const float* bl   = (const float*)d_in[5];
    const float* wr   = (const float*)d_in[6];
    const float* br   = (const float*)d_in[7];
    const float* wo   = (const float*)d_in[8];
    const float* bo   = (const float*)d_in[9];
    float* out = (float*)d_out;

    char* ws = (char*)d_ws;
    __bf16* leftT   = (__bf16*)(ws);             // 6,291,456
    __bf16* rightT  = (__bf16*)(ws + 6291456);   // 6,291,456
    __bf16* woT     = (__bf16*)(ws + 12582912);  // 262,144
    __bf16* wg      = (__bf16*)(ws + 12845056);  // 32,768
    float*  Gc      = (float*) (ws + 12877824);  // 256
    float*  B2      = (float*) (ws + 12878080);  // 256
    float*  inv_cnt = (float*) (ws + 12878336);  // 589,824 (end ~13.5 MB)

    prep_kernel<<<512, 256, 0, stream>>>(wo, woT);
    prep_wg_kernel<<<64, 256, 0, stream>>>(wl, wr, bl, br, ln_g, ln_b, wg, Gc, B2);
    cnt_kernel<<<NSEQ, 256, 0, stream>>>(mask, inv_cnt);
    ln_proj_kernel<<<NSEQ, 256, 0, stream>>>(x, mask, wg, Gc, B2, leftT, rightT);
    outer_gemm_kernel<<<2304, 512, 0, stream>>>(leftT, rightT, woT, bo, inv_cnt, out);
}